// Round 4
// baseline (550.817 us; speedup 1.0000x reference)
//
#include <hip/hip_runtime.h>

// ---------------------------------------------------------------------------
// Kernel A: i_x[t,b,n] = sum_k x[t,b,k] * w_in[k,n]
// Plain fp32 vector GEMM: M = T*B = 128000, K = 256, N = 256.
// Tile 128x128, 256 threads, 8x8 micro-tile per thread, BK=32.  (~112 TF)
// ---------------------------------------------------------------------------
__global__ __launch_bounds__(256) void gemm_xw(const float* __restrict__ X,
                                               const float* __restrict__ W,
                                               float* __restrict__ Y,
                                               int M) {
    __shared__ float As[32][132];
    __shared__ float Bs[32][128];

    const int tid = threadIdx.x;
    const int mb = blockIdx.x >> 1;
    const int nb = blockIdx.x & 1;
    const int m0 = mb << 7;
    const int n0 = nb << 7;
    const int tr = (tid >> 4) << 3;
    const int tc = (tid & 15) << 3;

    float acc[8][8];
#pragma unroll
    for (int i = 0; i < 8; ++i)
#pragma unroll
        for (int j = 0; j < 8; ++j) acc[i][j] = 0.f;

    for (int kb = 0; kb < 256; kb += 32) {
#pragma unroll
        for (int i = 0; i < 4; ++i) {
            int f = tid + (i << 8);
            int row = f >> 3, kq = f & 7;
            float4 a = *(const float4*)(X + (size_t)(m0 + row) * 256 + kb + (kq << 2));
            As[(kq << 2) + 0][row] = a.x;
            As[(kq << 2) + 1][row] = a.y;
            As[(kq << 2) + 2][row] = a.z;
            As[(kq << 2) + 3][row] = a.w;
            int rowb = f >> 5, cq = f & 31;
            *(float4*)&Bs[rowb][cq << 2] =
                *(const float4*)(W + (size_t)(kb + rowb) * 256 + n0 + (cq << 2));
        }
        __syncthreads();
#pragma unroll
        for (int k = 0; k < 32; ++k) {
            float a[8], b[8];
            *(float4*)&a[0] = *(const float4*)&As[k][tr];
            *(float4*)&a[4] = *(const float4*)&As[k][tr + 4];
            *(float4*)&b[0] = *(const float4*)&Bs[k][tc];
            *(float4*)&b[4] = *(const float4*)&Bs[k][tc + 4];
#pragma unroll
            for (int i = 0; i < 8; ++i)
#pragma unroll
                for (int j = 0; j < 8; ++j)
                    acc[i][j] = fmaf(a[i], b[j], acc[i][j]);
        }
        __syncthreads();
    }
#pragma unroll
    for (int i = 0; i < 8; ++i) {
        float* yp = Y + (size_t)(m0 + tr + i) * 256 + n0 + tc;
        *(float4*)yp = make_float4(acc[i][0], acc[i][1], acc[i][2], acc[i][3]);
        *(float4*)(yp + 4) = make_float4(acc[i][4], acc[i][5], acc[i][6], acc[i][7]);
    }
}

// ---------------------------------------------------------------------------
// Kernel B: sequential scan. ONE WAVE per sample, 4 neurons/lane, masks in
// SGPRs via __ballot. ix prefetched in 8-step chunks via INLINE-ASM
// global_load_dwordx4 (invisible to the compiler's waitcnt pass) with one
// manual s_waitcnt vmcnt(16) per chunk:
//   safe because >=16 stores are issued after the waited-on buffer's loads,
//   so outstanding<=16 => those loads retired (in-order completion), while
//   the freshly issued refill (16 newest ops max) may stay in flight.
// Common-path steps have NO waits at all; only spike steps (~25%) pay the
// compiler's conservative vmcnt(0) for the dynamic w_rec gather.
// i_x aliases the zs output region: refill for chunk k+1 reads rows
// t >= 8k+8 while stores so far touched t <= 8k+7 — never overlapping.
// ---------------------------------------------------------------------------
__global__ __launch_bounds__(64) void lif_seq(const float* __restrict__ ix,
                                              const float* __restrict__ wrec,
                                              const float* __restrict__ z0,
                                              const float* __restrict__ v0,
                                              const float* __restrict__ t0,
                                              float* __restrict__ zs,
                                              float* __restrict__ vs,
                                              int T, int B) {
    const int b = blockIdx.x;
    const int lane = threadIdx.x;
    const int nbase = lane << 2;
    const size_t sb = (size_t)b * 256 + nbase;
    const size_t stride = (size_t)B * 256;

    float4 v4 = *(const float4*)(v0 + sb);
    float4 t4 = *(const float4*)(t0 + sb);
    float4 z4 = *(const float4*)(z0 + sb);
    float v[4] = {v4.x, v4.y, v4.z, v4.w};
    float t[4] = {t4.x, t4.y, t4.z, t4.w};
    float z[4] = {z4.x, z4.y, z4.z, z4.w};

    unsigned long long mk0 = __ballot(z[0] != 0.f);
    unsigned long long mk1 = __ballot(z[1] != 0.f);
    unsigned long long mk2 = __ballot(z[2] != 0.f);
    unsigned long long mk3 = __ballot(z[3] != 0.f);

    const float* ixp = ix + sb;

    auto step = [&](int ts, float4 r) {
        // ---- sparse z @ w_rec (uniform masks -> scalar skip) ----
        float ir[4] = {0.f, 0.f, 0.f, 0.f};
        if (mk0 | mk1 | mk2 | mk3) {
            unsigned long long mm;
            mm = mk0;
            while (mm) { int j = __builtin_ctzll(mm); mm &= mm - 1;
                const float4 w = *(const float4*)(wrec + ((size_t)((j << 2) + 0) << 8) + nbase);
                ir[0] += w.x; ir[1] += w.y; ir[2] += w.z; ir[3] += w.w; }
            mm = mk1;
            while (mm) { int j = __builtin_ctzll(mm); mm &= mm - 1;
                const float4 w = *(const float4*)(wrec + ((size_t)((j << 2) + 1) << 8) + nbase);
                ir[0] += w.x; ir[1] += w.y; ir[2] += w.z; ir[3] += w.w; }
            mm = mk2;
            while (mm) { int j = __builtin_ctzll(mm); mm &= mm - 1;
                const float4 w = *(const float4*)(wrec + ((size_t)((j << 2) + 2) << 8) + nbase);
                ir[0] += w.x; ir[1] += w.y; ir[2] += w.z; ir[3] += w.w; }
            mm = mk3;
            while (mm) { int j = __builtin_ctzll(mm); mm &= mm - 1;
                const float4 w = *(const float4*)(wrec + ((size_t)((j << 2) + 3) << 8) + nbase);
                ir[0] += w.x; ir[1] += w.y; ir[2] += w.z; ir[3] += w.w; }
        }

        float rr[4] = {r.x, r.y, r.z, r.w};
        float nz[4];
#pragma unroll
        for (int c = 0; c < 4; ++c) {
            float i_in = rr[c] + ir[c];
            float h = (i_in != 0.f) ? 1.f : 0.f;
            float nt = t[c] + (1.f - h);
            float nv = (z[c] != 0.f) ? 0.f : v[c];          // reset on spike
            nv = fmaxf(nv, -1.f);                           // exact clamp at -1
            float cap = __builtin_amdgcn_exp2f(fabsf(nv)) - 1.f;   // A=B=C=1
            float arg = fminf(h * (nt + 1.f), cap);                // DT=1
            float L = __builtin_amdgcn_logf((1e-5f + arg) + 1.f);  // log2
            float sgn = (nv > 0.f) ? 1.f : ((nv < 0.f) ? -1.f : 0.f);
            nv = fmaf(-sgn, L, nv);                         // exact: sgn in {-1,0,1}
            nv = nv + i_in;
            nt = nt * (1.f - h);
            float zn = ((nv - 0.5f) > 0.f) ? 1.f : 0.f;     // spike fwd, THR=0.5
            v[c] = nv; t[c] = nt; z[c] = zn; nz[c] = zn;
        }
        mk0 = __ballot(nz[0] != 0.f);
        mk1 = __ballot(nz[1] != 0.f);
        mk2 = __ballot(nz[2] != 0.f);
        mk3 = __ballot(nz[3] != 0.f);

        size_t o = (size_t)ts * stride + sb;
        *(float4*)(zs + o) = make_float4(z[0], z[1], z[2], z[3]);  // overwrites ix[ts] after use
        *(float4*)(vs + o) = make_float4(v[0], v[1], v[2], v[3]);
    };

    float4 bufA[8], bufB[8];

#define ISSUE(BUF, C)                                                          \
    {                                                                          \
        _Pragma("unroll") for (int u = 0; u < 8; ++u) {                        \
            const float* p_ = ixp + (size_t)((C) * 8 + u) * stride;            \
            asm volatile("global_load_dwordx4 %0, %1, off"                     \
                         : "=v"(BUF[u]) : "v"(p_) : "memory");                 \
        }                                                                      \
    }

#define RUNC(BUF, K)                                                           \
    { _Pragma("unroll") for (int u = 0; u < 8; ++u) step((K) * 8 + u, BUF[u]); }

    const int NC = T >> 3;            // chunks of 8 (T=1000 -> 125, exact)

    ISSUE(bufA, 0);
    asm volatile("s_waitcnt vmcnt(0)" ::: "memory");
    __builtin_amdgcn_sched_barrier(0);

    for (int k = 0; k < NC; ++k) {
        // guarantee the buffer we're about to run is resident (see header)
        asm volatile("s_waitcnt vmcnt(16)" ::: "memory");
        __builtin_amdgcn_sched_barrier(0);
        int nc1 = (k + 1 < NC) ? k + 1 : NC - 1;   // clamped dummy refill at tail
        if ((k & 1) == 0) {
            ISSUE(bufB, nc1);
            RUNC(bufA, k);
        } else {
            ISSUE(bufA, nc1);
            RUNC(bufB, k);
        }
    }

    // remainder steps (T not multiple of 8): plain loads, compiler-managed
    for (int ts = NC << 3; ts < T; ++ts) {
        float4 r = *(const float4*)(ixp + (size_t)ts * stride);
        step(ts, r);
    }
#undef ISSUE
#undef RUNC
}

extern "C" void kernel_launch(void* const* d_in, const int* in_sizes, int n_in,
                              void* d_out, int out_size, void* d_ws, size_t ws_size,
                              hipStream_t stream) {
    const float* x    = (const float*)d_in[0];
    const float* z0   = (const float*)d_in[1];
    const float* v0   = (const float*)d_in[2];
    const float* t0   = (const float*)d_in[3];
    const float* w_in = (const float*)d_in[4];
    const float* wrec = (const float*)d_in[5];

    const int n_rec = 256;
    const int B = in_sizes[1] / n_rec;          // 128
    const int nin = in_sizes[4] / n_rec;        // 256
    const int T = in_sizes[0] / (B * nin);      // 1000
    const int M = T * B;                        // 128000

    float* zs = (float*)d_out;
    float* vs = zs + (size_t)T * B * n_rec;
    float* ixbuf = zs;  // stage x@w_in into the zs region (read-before-write in lif_seq)

    gemm_xw<<<dim3((M / 128) * 2), dim3(256), 0, stream>>>(x, w_in, ixbuf, M);
    lif_seq<<<dim3(B), dim3(64), 0, stream>>>(ixbuf, wrec, z0, v0, t0, zs, vs, T, B);
}

// Round 6
// 525.091 us; speedup vs baseline: 1.0490x; 1.0490x over previous
//
#include <hip/hip_runtime.h>

// ---------------------------------------------------------------------------
// Kernel A: i_x[t,b,n] = sum_k x[t,b,k] * w_in[k,n]
// Plain fp32 vector GEMM: M = T*B = 128000, K = 256, N = 256.  (~112 TF)
// ---------------------------------------------------------------------------
__global__ __launch_bounds__(256) void gemm_xw(const float* __restrict__ X,
                                               const float* __restrict__ W,
                                               float* __restrict__ Y,
                                               int M) {
    __shared__ float As[32][132];
    __shared__ float Bs[32][128];

    const int tid = threadIdx.x;
    const int mb = blockIdx.x >> 1;
    const int nb = blockIdx.x & 1;
    const int m0 = mb << 7;
    const int n0 = nb << 7;
    const int tr = (tid >> 4) << 3;
    const int tc = (tid & 15) << 3;

    float acc[8][8];
#pragma unroll
    for (int i = 0; i < 8; ++i)
#pragma unroll
        for (int j = 0; j < 8; ++j) acc[i][j] = 0.f;

    for (int kb = 0; kb < 256; kb += 32) {
#pragma unroll
        for (int i = 0; i < 4; ++i) {
            int f = tid + (i << 8);
            int row = f >> 3, kq = f & 7;
            float4 a = *(const float4*)(X + (size_t)(m0 + row) * 256 + kb + (kq << 2));
            As[(kq << 2) + 0][row] = a.x;
            As[(kq << 2) + 1][row] = a.y;
            As[(kq << 2) + 2][row] = a.z;
            As[(kq << 2) + 3][row] = a.w;
            int rowb = f >> 5, cq = f & 31;
            *(float4*)&Bs[rowb][cq << 2] =
                *(const float4*)(W + (size_t)(kb + rowb) * 256 + n0 + (cq << 2));
        }
        __syncthreads();
#pragma unroll
        for (int k = 0; k < 32; ++k) {
            float a[8], b[8];
            *(float4*)&a[0] = *(const float4*)&As[k][tr];
            *(float4*)&a[4] = *(const float4*)&As[k][tr + 4];
            *(float4*)&b[0] = *(const float4*)&Bs[k][tc];
            *(float4*)&b[4] = *(const float4*)&Bs[k][tc + 4];
#pragma unroll
            for (int i = 0; i < 8; ++i)
#pragma unroll
                for (int j = 0; j < 8; ++j)
                    acc[i][j] = fmaf(a[i], b[j], acc[i][j]);
        }
        __syncthreads();
    }
#pragma unroll
    for (int i = 0; i < 8; ++i) {
        float* yp = Y + (size_t)(m0 + tr + i) * 256 + n0 + tc;
        *(float4*)yp = make_float4(acc[i][0], acc[i][1], acc[i][2], acc[i][3]);
        *(float4*)(yp + 4) = make_float4(acc[i][4], acc[i][5], acc[i][6], acc[i][7]);
    }
}

// ---------------------------------------------------------------------------
// Kernel B: sequential scan. ONE WAVE per sample, 4 neurons/lane, SGPR masks
// via __ballot. Anti-store-hazard structure (the R1-R3 ~920cy/step wall was
// compiler-inserted vmcnt waits protecting store-source register reuse):
//   - 8-step chunks; ix loaded per chunk into plain double-buffered float4
//     arrays (compiler-visible -> counted vmcnt waits on chunk-old loads,
//     i.e. free). Outputs accumulate in zo/vo registers (static indices)
//     and burst-store once per chunk -> store-source registers are reused
//     a full chunk later, so hazard waits hit retired stores (free).
//   - spike gather = ONE fused asm (global_load_dwordx4 ; s_waitcnt
//     vmcnt(0)): value complete when the asm ends (no split-issue register
//     hazard), and invisible ops never linger (drained inside the asm), so
//     the compiler's counted waits stay sound. Its "memory" clobber also
//     pins chunk loads before the step loop.
// i_x aliases the zs region: chunk k's loads (rows 8k..8k+7 and prefetch
// 8k+8..) are issued before chunk k's stores (rows 8k..8k+7)... note loads
// of a chunk are issued BEFORE that chunk's own stores, and prefetch rows
// are always strictly ahead of all stores issued so far.
// ---------------------------------------------------------------------------
__global__ __launch_bounds__(64) void lif_seq(const float* __restrict__ ix,
                                              const float* __restrict__ wrec,
                                              const float* __restrict__ z0,
                                              const float* __restrict__ v0,
                                              const float* __restrict__ t0,
                                              float* __restrict__ zs,
                                              float* __restrict__ vs,
                                              int T, int B) {
    const int b = blockIdx.x;
    const int lane = threadIdx.x;
    const int nbase = lane << 2;
    const size_t sb = (size_t)b * 256 + nbase;
    const size_t stride = (size_t)B * 256;

    float4 v4 = *(const float4*)(v0 + sb);
    float4 t4 = *(const float4*)(t0 + sb);
    float4 z4 = *(const float4*)(z0 + sb);
    float v[4] = {v4.x, v4.y, v4.z, v4.w};
    float t[4] = {t4.x, t4.y, t4.z, t4.w};
    float z[4] = {z4.x, z4.y, z4.z, z4.w};

    unsigned long long mk0 = __ballot(z[0] != 0.f);
    unsigned long long mk1 = __ballot(z[1] != 0.f);
    unsigned long long mk2 = __ballot(z[2] != 0.f);
    unsigned long long mk3 = __ballot(z[3] != 0.f);

    const float* ixp = ix + sb;

    // fused issue+wait gather load: no split-asm register hazard
    auto wload = [&](int row) -> float4 {
        const float* wp = wrec + ((size_t)row << 8) + nbase;
        float4 w4;
        asm volatile("global_load_dwordx4 %0, %1, off\n\ts_waitcnt vmcnt(0)"
                     : "=v"(w4) : "v"(wp) : "memory");
        return w4;
    };

    // one LIF step: registers in, registers out (R3-proven math)
    auto step = [&](float4 r, float4& zo4, float4& vo4) {
        float ir[4] = {0.f, 0.f, 0.f, 0.f};
        if (mk0 | mk1 | mk2 | mk3) {
            unsigned long long mm;
            mm = mk0;
            while (mm) { int j = __builtin_ctzll(mm); mm &= mm - 1;
                float4 w = wload((j << 2) + 0);
                ir[0] += w.x; ir[1] += w.y; ir[2] += w.z; ir[3] += w.w; }
            mm = mk1;
            while (mm) { int j = __builtin_ctzll(mm); mm &= mm - 1;
                float4 w = wload((j << 2) + 1);
                ir[0] += w.x; ir[1] += w.y; ir[2] += w.z; ir[3] += w.w; }
            mm = mk2;
            while (mm) { int j = __builtin_ctzll(mm); mm &= mm - 1;
                float4 w = wload((j << 2) + 2);
                ir[0] += w.x; ir[1] += w.y; ir[2] += w.z; ir[3] += w.w; }
            mm = mk3;
            while (mm) { int j = __builtin_ctzll(mm); mm &= mm - 1;
                float4 w = wload((j << 2) + 3);
                ir[0] += w.x; ir[1] += w.y; ir[2] += w.z; ir[3] += w.w; }
        }

        float rr[4] = {r.x, r.y, r.z, r.w};
        float nzf[4], nvf[4];
#pragma unroll
        for (int c = 0; c < 4; ++c) {
            float i_in = rr[c] + ir[c];
            float h = (i_in != 0.f) ? 1.f : 0.f;
            float nt = t[c] + (1.f - h);
            float nv = (z[c] != 0.f) ? 0.f : v[c];          // reset on spike
            nv = fmaxf(nv, -1.f);                           // exact clamp at -1
            float cap = __builtin_amdgcn_exp2f(fabsf(nv)) - 1.f;   // A=B=C=1
            float arg = fminf(h * (nt + 1.f), cap);                // DT=1
            float L = __builtin_amdgcn_logf((1e-5f + arg) + 1.f);  // log2
            float sgn = (nv > 0.f) ? 1.f : ((nv < 0.f) ? -1.f : 0.f);
            nv = fmaf(-sgn, L, nv);                         // exact: sgn in {-1,0,1}
            nv = nv + i_in;
            nt = nt * (1.f - h);
            float zf = ((nv - 0.5f) > 0.f) ? 1.f : 0.f;     // spike fwd, THR=0.5
            v[c] = nv; t[c] = nt; z[c] = zf;
            nvf[c] = nv; nzf[c] = zf;
        }
        mk0 = __ballot(nzf[0] != 0.f);
        mk1 = __ballot(nzf[1] != 0.f);
        mk2 = __ballot(nzf[2] != 0.f);
        mk3 = __ballot(nzf[3] != 0.f);
        zo4 = make_float4(nzf[0], nzf[1], nzf[2], nzf[3]);
        vo4 = make_float4(nvf[0], nvf[1], nvf[2], nvf[3]);
    };

    float4 iA[8], iB[8];
    float4 zo[8], vo[8];

    auto loadChunk = [&](float4 (&ib)[8], int c0) {
#pragma unroll
        for (int u = 0; u < 8; ++u) {
            int r = c0 + u;
            r = (r < T) ? r : T - 1;
            ib[u] = *(const float4*)(ixp + (size_t)r * stride);
        }
    };

    auto runChunk = [&](float4 (&ib)[8], int c0) {
#pragma unroll
        for (int u = 0; u < 8; ++u) step(ib[u], zo[u], vo[u]);
        // burst store (overwrites consumed ix rows c0..c0+7)
        size_t ob = (size_t)c0 * stride + sb;
#pragma unroll
        for (int u = 0; u < 8; ++u) {
            *(float4*)(zs + ob + (size_t)u * stride) = zo[u];
            *(float4*)(vs + ob + (size_t)u * stride) = vo[u];
        }
    };

    loadChunk(iA, 0);
    int c = 0;
    while (c + 16 <= T) {
        loadChunk(iB, c + 8);
        runChunk(iA, c);
        loadChunk(iA, c + 16);   // clamped prefetch (dummy rows never consumed)
        runChunk(iB, c + 8);
        c += 16;
    }
    if (c + 8 <= T) {            // one leftover full chunk
        runChunk(iA, c);         // iA already holds rows c..c+7
        c += 8;
    }
    for (int ts = c; ts < T; ++ts) {   // remainder: plain per-step path
        float4 r = *(const float4*)(ixp + (size_t)ts * stride);
        float4 zz, vv;
        step(r, zz, vv);
        size_t o = (size_t)ts * stride + sb;
        *(float4*)(zs + o) = zz;
        *(float4*)(vs + o) = vv;
    }
}

extern "C" void kernel_launch(void* const* d_in, const int* in_sizes, int n_in,
                              void* d_out, int out_size, void* d_ws, size_t ws_size,
                              hipStream_t stream) {
    const float* x    = (const float*)d_in[0];
    const float* z0   = (const float*)d_in[1];
    const float* v0   = (const float*)d_in[2];
    const float* t0   = (const float*)d_in[3];
    const float* w_in = (const float*)d_in[4];
    const float* wrec = (const float*)d_in[5];

    const int n_rec = 256;
    const int B = in_sizes[1] / n_rec;          // 128
    const int nin = in_sizes[4] / n_rec;        // 256
    const int T = in_sizes[0] / (B * nin);      // 1000
    const int M = T * B;                        // 128000

    float* zs = (float*)d_out;
    float* vs = zs + (size_t)T * B * n_rec;
    float* ixbuf = zs;  // stage x@w_in into the zs region (read-before-write in lif_seq)

    gemm_xw<<<dim3((M / 128) * 2), dim3(256), 0, stream>>>(x, w_in, ixbuf, M);
    lif_seq<<<dim3(B), dim3(64), 0, stream>>>(ixbuf, wrec, z0, v0, t0, zs, vs, T, B);
}